// Round 9
// baseline (126.815 us; speedup 1.0000x reference)
//
#include <hip/hip_runtime.h>

// Self-attention (SAGAN-style), B=16, C=64, H=W=64. d8=8, d2=32, N=4096, M=1024.
// Round 9: proj pool_l fp32 -> bf16 (LDS 54.8 -> 44.3 KB => 3 blocks/CU).
// Max-pool commutes with monotone RNE rounding, so outputs are bit-identical.
// attn unchanged from round 8 (passed, absmax 0.03125). This is a plateau
// test: harness fill (268 MB @ 76% HBM peak, ~44 us) + dispatch overhead now
// dominate the iteration; kernel-addressable time is ~15-20 us total.

#define B_   16
#define C_   64
#define HW_  4096
#define M_   1024

typedef __attribute__((ext_vector_type(8))) short bf16x8;
typedef __attribute__((ext_vector_type(4))) float f32x4;

__device__ __forceinline__ unsigned short f2bf(float f) {   // RNE
    union { float f; unsigned int u; } v; v.f = f;
    return (unsigned short)((v.u + 0x7FFFu + ((v.u >> 16) & 1u)) >> 16);
}
__device__ __forceinline__ float bf2f(unsigned short s) {
    union { unsigned int u; float f; } v; v.u = ((unsigned int)s) << 16;
    return v.f;
}
__device__ __forceinline__ unsigned int pack2(float a, float b) {   // RNE pair
    return (unsigned int)f2bf(a) | ((unsigned int)f2bf(b) << 16);
}
__device__ __forceinline__ unsigned int pack2t(float a, float b) {  // trunc pair
    union { float f; unsigned int u; } ua, ub; ua.f = a; ub.f = b;
    return (ua.u >> 16) | (ub.u & 0xFFFF0000u);
}

// ---------------------------------------------------------------------------
// proj: thetaB(B,N,8) bf16 compact; phiB32(B,1024,32) bf16 with cols 8..31=0;
// gTp(B,32,1024) bf16 with m permuted per 32-block: ms=m&31,
// p = (m&~31) + ((ms>>2)&3)*8 + (ms>>4)*4 + (ms&3).
// LDS: x_l 33.8 KB fp32 + pool_l 10.5 KB bf16 = 44.3 KB -> 3 blocks/CU.
// ---------------------------------------------------------------------------
__global__ __launch_bounds__(256) void proj_kernel(
    const float* __restrict__ x,
    const float* __restrict__ w_theta, const float* __restrict__ b_theta,
    const float* __restrict__ w_phi,   const float* __restrict__ b_phi,
    const float* __restrict__ w_g,     const float* __restrict__ b_g,
    unsigned short* __restrict__ thetaB,
    unsigned short* __restrict__ phiB32,
    unsigned short* __restrict__ gTp)
{
    __shared__ __align__(16) float x_l[64 * 132];     // [c][px] stride 132
    __shared__ unsigned short pool_l[128][41];        // bf16: 0..7 phi, 8..39 g

    const int tid = threadIdx.x;
    const int b   = blockIdx.y;
    const int rp  = blockIdx.x;          // row pair 0..31
    const int n0  = rp * 128;

    // stage x tile: 64 ch x 128 px, coalesced float4
    {
        const float4* src = (const float4*)(x + (size_t)b * C_ * HW_ + n0);
        #pragma unroll
        for (int j = 0; j < 8; j++) {
            int idx = tid + j * 256;
            int c = idx >> 5, p4 = idx & 31;
            float4 v = src[(size_t)c * (HW_ / 4) + p4];
            *(float4*)&x_l[c * 132 + p4 * 4] = v;
        }
    }
    __syncthreads();

    const int px = tid & 127;
    const int og = tid >> 7;             // wave-uniform half

    if (og == 0) {
        float th[8], ph[8], g0[8];
        #pragma unroll
        for (int o = 0; o < 8; o++) { th[o] = b_theta[o]; ph[o] = b_phi[o]; g0[o] = b_g[o]; }
        #pragma unroll 4
        for (int c = 0; c < C_; c++) {
            float xv = x_l[c * 132 + px];
            #pragma unroll
            for (int o = 0; o < 8; o++) th[o] += xv * w_theta[o * 64 + c];
            #pragma unroll
            for (int o = 0; o < 8; o++) ph[o] += xv * w_phi[o * 64 + c];
            #pragma unroll
            for (int o = 0; o < 8; o++) g0[o] += xv * w_g[o * 64 + c];
        }
        unsigned short* tout = thetaB + ((size_t)b * HW_ + n0 + px) * 8;
        uint4 tv;
        tv.x = pack2(th[0], th[1]); tv.y = pack2(th[2], th[3]);
        tv.z = pack2(th[4], th[5]); tv.w = pack2(th[6], th[7]);
        *(uint4*)tout = tv;
        #pragma unroll
        for (int o = 0; o < 8; o++) {
            pool_l[px][o]     = f2bf(ph[o]);
            pool_l[px][8 + o] = f2bf(g0[o]);
        }
    } else {
        float gg[24];
        #pragma unroll
        for (int o = 0; o < 24; o++) gg[o] = b_g[8 + o];
        #pragma unroll 4
        for (int c = 0; c < C_; c++) {
            float xv = x_l[c * 132 + px];
            #pragma unroll
            for (int o = 0; o < 24; o++) gg[o] += xv * w_g[(8 + o) * 64 + c];
        }
        #pragma unroll
        for (int o = 0; o < 24; o++) pool_l[px][16 + o] = f2bf(gg[o]);
    }
    __syncthreads();

    // parallel 2x2 max-pool over all 256 threads:
    // j = pooled col (0..31), grp = tid>>5 (0..7) handles channels grp*5..grp*5+4
    {
        const int j   = tid & 31;
        const int grp = tid >> 5;
        const int p00 = 2 * j, p01 = 2 * j + 1, p10 = 64 + 2 * j, p11 = 65 + 2 * j;
        const int mq   = rp * 32 + j;
        const int pcol = rp * 32 + ((j >> 2) & 3) * 8 + (j >> 4) * 4 + (j & 3);
        #pragma unroll
        for (int k = 0; k < 5; k++) {
            const int ch = grp * 5 + k;          // 0..39 exactly
            float v = fmaxf(fmaxf(bf2f(pool_l[p00][ch]), bf2f(pool_l[p01][ch])),
                            fmaxf(bf2f(pool_l[p10][ch]), bf2f(pool_l[p11][ch])));
            if (ch < 8)
                phiB32[((size_t)b * M_ + mq) * 32 + ch] = f2bf(v);
            else
                gTp[((size_t)b * 32 + (ch - 8)) * M_ + pcol] = f2bf(v);
        }
        // zero phi k-pads (cols 8..31): 32 m x 3 uint4
        if (tid < 96) {
            const int m = tid / 3, seg = tid % 3;
            *(uint4*)(phiB32 + ((size_t)b * M_ + rp * 32 + m) * 32 + 8 + seg * 8) =
                make_uint4(0, 0, 0, 0);
        }
    }
}

// ---------------------------------------------------------------------------
// attn: block = (batch, 64-q tile), 256 thr = 4 waves. Wave wv privately owns
// m-chunks wv*4..wv*4+3; per chunk: 8 global b128 loads (reused over 4
// q-tiles), 16 score + 16 PV MFMAs, 64 exp. Register P remap: S^T C-layout
// == PV B-frag with k=quad*8+j <-> m = s*32 + (j>>2)*16 + quad*4 + (j&3).
// Partial O^T / rowsum per wave; cross-wave reduce in epilogue.
// ---------------------------------------------------------------------------
__global__ __launch_bounds__(256, 4) void attn_kernel(
    const float* __restrict__ x,
    const unsigned short* __restrict__ thetaB,   // [b][n][8]
    const unsigned short* __restrict__ phiB32,   // [b][m][32], cols 8..31 = 0
    const unsigned short* __restrict__ gTp,      // [b][c][1024] m-permuted
    const float* __restrict__ w_o, const float* __restrict__ b_o,
    const float* __restrict__ sigma,
    float* __restrict__ out)
{
    __shared__ float Op_l[4][64 * 33];   // [wv][q][c] partial O
    __shared__ float rs_l[4][64];        // [wv][q] partial rowsums

    const int tid   = threadIdx.x;
    const int b     = blockIdx.y;
    const int qbase = blockIdx.x * 64;
    const int wv    = tid >> 6;
    const int lane  = tid & 63;
    const int ln15  = lane & 15;
    const int quad  = lane >> 4;

    const unsigned short* phiP = phiB32 + (size_t)b * M_ * 32;
    const unsigned short* gP   = gTp    + (size_t)b * 32 * M_;

    // theta B-frags for the 4 q-tiles (loaded once; quad 0 real, rest zero)
    bf16x8 th[4];
    {
        const bf16x8 z = {0, 0, 0, 0, 0, 0, 0, 0};
        #pragma unroll
        for (int qt = 0; qt < 4; qt++) {
            const unsigned short* tp =
                thetaB + ((size_t)b * HW_ + qbase + qt * 16 + ln15) * 8;
            bf16x8 t = *(const bf16x8*)tp;
            th[qt] = (quad == 0) ? t : z;
        }
    }

    #define LD_PHI(ch_, mt_) \
        (*(const bf16x8*)(phiP + ((size_t)((ch_) * 64 + (mt_) * 16 + ln15)) * 32 + quad * 8))
    #define LD_G(ch_, h_, s_) \
        (*(const bf16x8*)(gP + (size_t)((h_) * 16 + ln15) * M_ + (ch_) * 64 + (s_) * 32 + quad * 8))

    f32x4 acc[2][4];                     // [c-half][q-tile], O^T partial
    #pragma unroll
    for (int h = 0; h < 2; h++)
        #pragma unroll
        for (int qt = 0; qt < 4; qt++) acc[h][qt] = (f32x4){0.f, 0.f, 0.f, 0.f};
    float rs_p[4] = {0.f, 0.f, 0.f, 0.f};

    #pragma unroll
    for (int wc = 0; wc < 4; wc++) {
        const int ch = wv * 4 + wc;
        bf16x8 pf[4];
        #pragma unroll
        for (int mt = 0; mt < 4; mt++) pf[mt] = LD_PHI(ch, mt);
        bf16x8 gf[2][2];
        gf[0][0] = LD_G(ch, 0, 0); gf[0][1] = LD_G(ch, 0, 1);
        gf[1][0] = LD_G(ch, 1, 0); gf[1][1] = LD_G(ch, 1, 1);

        #pragma unroll
        for (int s = 0; s < 2; s++) {
            #pragma unroll
            for (int qt = 0; qt < 4; qt++) {
                const f32x4 zc = {0.f, 0.f, 0.f, 0.f};
                f32x4 S0 = __builtin_amdgcn_mfma_f32_16x16x32_bf16(pf[2 * s],     th[qt], zc, 0, 0, 0);
                f32x4 S1 = __builtin_amdgcn_mfma_f32_16x16x32_bf16(pf[2 * s + 1], th[qt], zc, 0, 0, 0);
                float e0[4], e1[4];
                #pragma unroll
                for (int r = 0; r < 4; r++) {
                    e0[r] = __expf(S0[r]);
                    e1[r] = __expf(S1[r]);
                    rs_p[qt] += e0[r] + e1[r];
                }
                union { bf16x8 v; unsigned int u[4]; } pb;
                pb.u[0] = pack2t(e0[0], e0[1]); pb.u[1] = pack2t(e0[2], e0[3]);
                pb.u[2] = pack2t(e1[0], e1[1]); pb.u[3] = pack2t(e1[2], e1[3]);
                acc[0][qt] = __builtin_amdgcn_mfma_f32_16x16x32_bf16(gf[0][s], pb.v, acc[0][qt], 0, 0, 0);
                acc[1][qt] = __builtin_amdgcn_mfma_f32_16x16x32_bf16(gf[1][s], pb.v, acc[1][qt], 0, 0, 0);
            }
        }
    }
    #undef LD_PHI
    #undef LD_G

    // rowsum partials: reduce over quads (m-rows) within the wave
    {
        float v[4];
        #pragma unroll
        for (int qt = 0; qt < 4; qt++) {
            float t = rs_p[qt];
            t += __shfl_xor(t, 16);
            t += __shfl_xor(t, 32);
            v[qt] = t;
        }
        if (quad == 0) {
            #pragma unroll
            for (int qt = 0; qt < 4; qt++) rs_l[wv][qt * 16 + ln15] = v[qt];
        }
    }
    // O^T partials -> LDS: lane owns col q=qt*16+ln15, rows c=h*16+quad*4+r
    #pragma unroll
    for (int h = 0; h < 2; h++)
        #pragma unroll
        for (int qt = 0; qt < 4; qt++)
            #pragma unroll
            for (int r = 0; r < 4; r++)
                Op_l[wv][(qt * 16 + ln15) * 33 + h * 16 + quad * 4 + r] = acc[h][qt][r];
    __syncthreads();

    // epilogue: cross-wave reduce + normalize + w_o conv + bias + residual
    const int q = tid & 63;
    const float rowsum = rs_l[0][q] + rs_l[1][q] + rs_l[2][q] + rs_l[3][q];
    const float sg  = sigma[0];
    const float inv = sg / rowsum;
    float o[32];
    #pragma unroll
    for (int c = 0; c < 32; c++)
        o[c] = Op_l[0][q * 33 + c] + Op_l[1][q * 33 + c]
             + Op_l[2][q * 33 + c] + Op_l[3][q * 33 + c];
    const size_t xb = (size_t)b * C_ * HW_ + qbase + q;
    #pragma unroll
    for (int k = 0; k < 16; k++) {
        const int co = wv * 16 + k;
        float t = 0.f;
        #pragma unroll
        for (int c = 0; c < 32; c++) t += w_o[co * 32 + c] * o[c];
        out[xb + (size_t)co * HW_] = x[xb + (size_t)co * HW_] + t * inv + sg * b_o[co];
    }
}

// ---------------------------------------------------------------------------
extern "C" void kernel_launch(void* const* d_in, const int* in_sizes, int n_in,
                              void* d_out, int out_size, void* d_ws, size_t ws_size,
                              hipStream_t stream)
{
    const float* x       = (const float*)d_in[0];
    const float* w_theta = (const float*)d_in[1];
    const float* b_theta = (const float*)d_in[2];
    const float* w_phi   = (const float*)d_in[3];
    const float* b_phi   = (const float*)d_in[4];
    const float* w_g     = (const float*)d_in[5];
    const float* b_g     = (const float*)d_in[6];
    const float* w_o     = (const float*)d_in[7];
    const float* b_o     = (const float*)d_in[8];
    const float* sigma   = (const float*)d_in[9];
    float* out = (float*)d_out;

    // workspace (bf16): theta 1 MB, phi32 1 MB, gTp 1 MB
    unsigned short* thetaB = (unsigned short*)d_ws;
    unsigned short* phiB32 = thetaB + (size_t)B_ * HW_ * 8;
    unsigned short* gTp    = phiB32 + (size_t)B_ * M_ * 32;

    proj_kernel<<<dim3(32, B_), 256, 0, stream>>>(
        x, w_theta, b_theta, w_phi, b_phi, w_g, b_g, thetaB, phiB32, gTp);
    attn_kernel<<<dim3(64, B_), 256, 0, stream>>>(
        x, thetaB, phiB32, gTp, w_o, b_o, sigma, out);
}